// Round 20
// baseline (1998.440 us; speedup 1.0000x reference)
//
#include <hip/hip_runtime.h>
#include <hip/hip_bf16.h>

// ---------- types ----------
typedef __bf16 bf16x8 __attribute__((ext_vector_type(8)));
typedef float  f32x4  __attribute__((ext_vector_type(4)));

__device__ __forceinline__ unsigned short f2b(float f) {
  __hip_bfloat16 h = __float2bfloat16(f);
  return __builtin_bit_cast(unsigned short, h);
}
__device__ __forceinline__ float b2f(unsigned short u) {
  unsigned int v = ((unsigned int)u) << 16;
  return __builtin_bit_cast(float, v);
}

constexpr int T_DIM = 2000;
constexpr int BN    = 128;   // B*N = 32*4

// ---------- weight conversion (frag-order for W1/Sw/W2) ----------
__device__ __forceinline__ void swz8(const float* __restrict__ src, int srcK,
                                     int rowblk, int kblk, int lane,
                                     unsigned short* dst8) {
  int row = rowblk * 16 + (lane & 15);
  int k0  = kblk * 32 + (lane >> 4) * 8;
  #pragma unroll
  for (int j = 0; j < 8; ++j) {
    int k = k0 + j;
    dst8[j] = (k < srcK) ? f2b(src[row * srcK + k]) : (unsigned short)0;
  }
}

__global__ __launch_bounds__(256)
void cvt_weights(const float* __restrict__ e0w, const float* __restrict__ ew,
                 const float* __restrict__ sw,  const float* __restrict__ e2w,
                 unsigned short* __restrict__ out) {
  const int G0 = 512 * 128 / 8;        // expand0 (K padded to 128)
  const int G1 = 5 * 512 * 256 / 8;    // expand_w
  const int G2 = 6 * 256 * 512 / 8;    // shrink_w
  const int G3 = 512 * 256 / 8;        // expand2_w
  int g = blockIdx.x * 256 + threadIdx.x;
  if (g >= G0 + G1 + G2 + G3) return;

  unsigned short tmp[8];
  if (g < G0) {
    int lane = g & 63, fid = g >> 6;       // KB=4
    int kblk = fid & 3, rowblk = fid >> 2;
    swz8(e0w, 120, rowblk, kblk, lane, tmp);
  } else if (g < G0 + G1) {
    int gg = g - G0;
    int mat = gg / 16384, r = gg % 16384;  // KB=8
    int lane = r & 63, fid = r >> 6;
    int kblk = fid & 7, rowblk = fid >> 3;
    swz8(ew + (size_t)mat * 512 * 256, 256, rowblk, kblk, lane, tmp);
  } else if (g < G0 + G1 + G2) {
    int gg = g - G0 - G1;
    int mat = gg / 16384, r = gg % 16384;  // KB=16
    int lane = r & 63, fid = r >> 6;
    int kblk = fid & 15, rowblk = fid >> 4;
    swz8(sw + (size_t)mat * 256 * 512, 512, rowblk, kblk, lane, tmp);
  } else {
    int gg = g - G0 - G1 - G2;             // W2 512x256, KB=8
    int lane = gg & 63, fid = gg >> 6;
    int kblk = fid & 7, rowblk = fid >> 3;
    swz8(e2w, 256, rowblk, kblk, lane, tmp);
  }
  #pragma unroll
  for (int j = 0; j < 8; ++j) out[(size_t)g * 8 + j] = tmp[j];
}

// ---------- fused expand(+relu) -> shrink, 64-row tile, 8 waves (r18) ------
template<int KIN, bool L0>
__global__ __launch_bounds__(512, 4)
void layer_fused(const void* __restrict__ hin_v,          // L0: f32 x; else bf16 h
                 const unsigned short* __restrict__ W1,  // frag-order [512][KIN]
                 const float* __restrict__ b1,           // [512]
                 const unsigned short* __restrict__ Sw,  // frag-order [256][512]
                 unsigned short* __restrict__ sout)      // [BN,T,256] bf16
{
  constexpr int APAD = KIN + 8;
  constexpr int EPAD = 136;
  constexpr int KB1  = KIN / 32;       // 4 (L0) or 8
  constexpr int PB   = (KB1 < 4) ? KB1 : 4;   // prefetch batch size
  __shared__ unsigned short Alds[64 * APAD];
  __shared__ unsigned short Elds[64 * EPAD];

  const int bn  = blockIdx.x;
  const int t0  = blockIdx.y * 64;
  const int tid = threadIdx.x;

  if constexpr (L0) {
    const float* hin = (const float*)hin_v;
    constexpr int QUADS = KIN / 4;
    for (int idx = tid; idx < 64 * QUADS; idx += 512) {
      int row = idx / QUADS, q = idx % QUADS;
      int t = t0 + row;
      float4 v = make_float4(0.f, 0.f, 0.f, 0.f);
      if (t < T_DIM && q < 30) {
        const float* p = hin + ((size_t)((bn >> 2) * T_DIM + t) * 4 + (bn & 3)) * 120 + q * 4;
        v = *reinterpret_cast<const float4*>(p);
      }
      ushort4 u;
      u.x = f2b(v.x); u.y = f2b(v.y); u.z = f2b(v.z); u.w = f2b(v.w);
      *reinterpret_cast<ushort4*>(&Alds[row * APAD + q * 4]) = u;
    }
  } else {
    const unsigned short* hin = (const unsigned short*)hin_v;
    for (int idx = tid; idx < 64 * 32; idx += 512) {   // 32 x 8-ushort groups/row
      int row = idx >> 5, g = idx & 31;
      int t = t0 + row;
      uint4 v = make_uint4(0, 0, 0, 0);
      if (t < T_DIM)
        v = *reinterpret_cast<const uint4*>(hin + ((size_t)bn * T_DIM + t) * 256 + g * 8);
      *reinterpret_cast<uint4*>(&Alds[row * APAD + g * 8]) = v;
    }
  }

  const int w    = tid >> 6;          // wave 0..7
  const int lane = tid & 63;
  const int lr   = lane & 15;
  const int lk   = (lane >> 4) * 8;
  const int rgrp = (lane >> 4) * 4;

  auto ldW1 = [&](int c, int kb) {
    int rowblk = c * 8 + w;
    return *reinterpret_cast<const bf16x8*>(W1 + ((size_t)(rowblk * KB1 + kb) * 64 + lane) * 8);
  };

  bf16x8 w1p[PB];
  #pragma unroll
  for (int u = 0; u < PB; ++u) w1p[u] = ldW1(0, u);

  __syncthreads();

  f32x4 acc2[2][4];                   // [pt][m]
  #pragma unroll
  for (int pt = 0; pt < 2; ++pt)
    #pragma unroll
    for (int m = 0; m < 4; ++m) acc2[pt][m] = (f32x4){0.f, 0.f, 0.f, 0.f};

  #pragma unroll
  for (int c = 0; c < 4; ++c) {
    // ---- phase 1 (swapped): acc1[m][i] = E[t=m*16+lr][ecol=w*16+rgrp+i] ----
    f32x4 acc1[4];
    {
      float4 bv = *reinterpret_cast<const float4*>(&b1[c * 128 + w * 16 + rgrp]);
      #pragma unroll
      for (int m = 0; m < 4; ++m) acc1[m] = (f32x4){bv.x, bv.y, bv.z, bv.w};
    }
    #pragma unroll
    for (int u = 0; u < PB; ++u) {
      #pragma unroll
      for (int m = 0; m < 4; ++m) {
        bf16x8 a = *reinterpret_cast<const bf16x8*>(&Alds[(m * 16 + lr) * APAD + u * 32 + lk]);
        acc1[m] = __builtin_amdgcn_mfma_f32_16x16x32_bf16(w1p[u], a, acc1[m], 0, 0, 0);
      }
    }
    if constexpr (KB1 > PB) {
      bf16x8 bfr[KB1 - PB];
      #pragma unroll
      for (int u = 0; u < KB1 - PB; ++u) bfr[u] = ldW1(c, PB + u);
      #pragma unroll
      for (int u = 0; u < KB1 - PB; ++u) {
        #pragma unroll
        for (int m = 0; m < 4; ++m) {
          bf16x8 a = *reinterpret_cast<const bf16x8*>(&Alds[(m * 16 + lr) * APAD + (PB + u) * 32 + lk]);
          acc1[m] = __builtin_amdgcn_mfma_f32_16x16x32_bf16(bfr[u], a, acc1[m], 0, 0, 0);
        }
      }
    }
    // relu + packed ushort4 write: row = m*16+lr, cols = w*16+rgrp..+3
    #pragma unroll
    for (int m = 0; m < 4; ++m) {
      ushort4 u4;
      float v0 = acc1[m][0]; v0 = v0 > 0.f ? v0 : 0.f;
      float v1 = acc1[m][1]; v1 = v1 > 0.f ? v1 : 0.f;
      float v2 = acc1[m][2]; v2 = v2 > 0.f ? v2 : 0.f;
      float v3 = acc1[m][3]; v3 = v3 > 0.f ? v3 : 0.f;
      u4.x = f2b(v0); u4.y = f2b(v1); u4.z = f2b(v2); u4.w = f2b(v3);
      *reinterpret_cast<ushort4*>(&Elds[(m * 16 + lr) * EPAD + w * 16 + rgrp]) = u4;
    }
    // phase-2 B batch A (kb2 0..1), issued before the barrier
    bf16x8 b2a[4];
    #pragma unroll
    for (int u = 0; u < 4; ++u) {              // kb2 = u>>1, pt = u&1
      int rowblk = w * 2 + (u & 1);
      int kblk   = c * 4 + (u >> 1);
      b2a[u] = *reinterpret_cast<const bf16x8*>(Sw + ((size_t)(rowblk * 16 + kblk) * 64 + lane) * 8);
    }
    __syncthreads();
    // phase-2 B batch B (kb2 2..3) + next-c W1 prefetch under phase-2 MFMAs
    bf16x8 b2b[4];
    #pragma unroll
    for (int u = 0; u < 4; ++u) {
      int rowblk = w * 2 + (u & 1);
      int kblk   = c * 4 + 2 + (u >> 1);
      b2b[u] = *reinterpret_cast<const bf16x8*>(Sw + ((size_t)(rowblk * 16 + kblk) * 64 + lane) * 8);
    }
    if (c < 3) {
      #pragma unroll
      for (int u = 0; u < PB; ++u) w1p[u] = ldW1(c + 1, u);
    }
    // ---- phase 2: S cols [w*32,+32) += E_chunk * Sw^T ----
    #pragma unroll
    for (int kq = 0; kq < 2; ++kq) {
      bf16x8 a2[4];
      #pragma unroll
      for (int m = 0; m < 4; ++m)
        a2[m] = *reinterpret_cast<const bf16x8*>(&Elds[(m * 16 + lr) * EPAD + kq * 32 + lk]);
      #pragma unroll
      for (int pt = 0; pt < 2; ++pt)
        #pragma unroll
        for (int m = 0; m < 4; ++m)
          acc2[pt][m] = __builtin_amdgcn_mfma_f32_16x16x32_bf16(a2[m], b2a[kq * 2 + pt], acc2[pt][m], 0, 0, 0);
    }
    #pragma unroll
    for (int kq = 0; kq < 2; ++kq) {
      bf16x8 a2[4];
      #pragma unroll
      for (int m = 0; m < 4; ++m)
        a2[m] = *reinterpret_cast<const bf16x8*>(&Elds[(m * 16 + lr) * EPAD + (2 + kq) * 32 + lk]);
      #pragma unroll
      for (int pt = 0; pt < 2; ++pt)
        #pragma unroll
        for (int m = 0; m < 4; ++m)
          acc2[pt][m] = __builtin_amdgcn_mfma_f32_16x16x32_bf16(a2[m], b2b[kq * 2 + pt], acc2[pt][m], 0, 0, 0);
    }
    if (c < 3) __syncthreads();   // single Elds: drain reads before next write
  }

  // epilogue: col = w*32 + pt*16 + lr, t = t0 + m*16 + rgrp + i
  #pragma unroll
  for (int pt = 0; pt < 2; ++pt)
    #pragma unroll
    for (int m = 0; m < 4; ++m)
      #pragma unroll
      for (int i = 0; i < 4; ++i) {
        int t = t0 + m * 16 + rgrp + i;
        if (t < T_DIM)
          sout[((size_t)bn * T_DIM + t) * 256 + w * 32 + pt * 16 + lr] = f2b(acc2[pt][m][i]);
      }
}

// ---------- FSMN memory block + residual (h bf16), rolling reg window ------
template<bool RES, bool GUARD>
__device__ __forceinline__ void fsmn_body(const unsigned short* __restrict__ scol,
                                          unsigned short* __restrict__ hcol, int t0,
                                          const float* wlv, float wrv) {
  float sv[40];
  #pragma unroll
  for (int j = 0; j < 40; ++j) {
    int t = t0 + j - 19;
    sv[j] = (!GUARD || ((unsigned)t < (unsigned)T_DIM)) ? b2f(scol[(ptrdiff_t)t * 256]) : 0.f;
  }
  #pragma unroll 1
  for (int ch = 0; ch < 10; ++ch) {
    int tb = t0 + ch * 20;
    #pragma unroll
    for (int j = 0; j < 20; ++j) {
      float acc = sv[j + 19] + wrv * sv[j + 20];
      #pragma unroll
      for (int k = 0; k < 20; ++k) acc += wlv[k] * sv[j + k];
      size_t off = (size_t)(tb + j) * 256;
      float prev = RES ? b2f(hcol[off]) : 0.f;
      hcol[off] = f2b(prev + acc);
    }
    if (ch < 9) {
      #pragma unroll
      for (int j = 0; j < 20; ++j) sv[j] = sv[j + 20];
      #pragma unroll
      for (int j = 20; j < 40; ++j) {
        int t = tb + j + 1;
        sv[j] = (!GUARD || ((unsigned)t < (unsigned)T_DIM)) ? b2f(scol[(ptrdiff_t)t * 256]) : 0.f;
      }
    }
  }
}

template<bool RES>
__global__ __launch_bounds__(256)
void fsmn_kernel(const unsigned short* __restrict__ s,
                 const float* __restrict__ wl,
                 const float* __restrict__ wr,
                 unsigned short* __restrict__ hbuf)   // bf16 h
{
  const int bn = blockIdx.x;
  const int t0 = blockIdx.y * 200;
  const int p  = threadIdx.x;

  float wlv[20];
  #pragma unroll
  for (int k = 0; k < 20; ++k) wlv[k] = wl[p * 20 + k];
  const float wrv = wr[p];

  const unsigned short* scol = s + (size_t)bn * T_DIM * 256 + p;
  unsigned short* hcol = hbuf + (size_t)bn * T_DIM * 256 + p;

  bool safe = (t0 >= 19) && (t0 + 200 <= T_DIM - 1);
  if (safe) fsmn_body<RES, false>(scol, hcol, t0, wlv, wrv);
  else      fsmn_body<RES, true >(scol, hcol, t0, wlv, wrv);
}

// ---------- expand2 + relu + channel-max + decoder (fused; h bf16) ----------
// Channels staged in PAIRS (67.6 KB LDS -> 2 blk/CU, was 135 KB @ 1 blk/CU);
// Y stored bf16 in the same buffer for the decoder. VGPR capped 128 via
// (512,4) — peak live ~110 (acc[4] per pt; dwv after ymax dies).
__global__ __launch_bounds__(512, 4)
void expand2_max_dec(const unsigned short* __restrict__ hbuf,  // [BN,T,256] bf16
                     const unsigned short* __restrict__ W2f,   // frag-order [512][256]
                     const float* __restrict__ b2,             // [512]
                     const float* __restrict__ dwt,            // [9][512]
                     const float* __restrict__ dbv,            // [9]
                     float* __restrict__ z)                    // [32,T,9]
{
  constexpr int EPAD = 264;   // per-channel ushort row stride
  constexpr int YPAD = 520;   // bf16 Y row stride (ushort)
  __shared__ unsigned short smem[2 * 64 * EPAD];   // 67584 B; Y reuse 64*520*2=66560 B

  const int b   = blockIdx.x;
  const int t0  = blockIdx.y * 64;
  const int tid = threadIdx.x;

  const int w    = tid >> 6;
  const int lane = tid & 63;
  const int lr   = lane & 15;
  const int lk   = (lane >> 4) * 8;
  const int rgrp = (lane >> 4) * 4;

  auto stage_pair = [&](int n0) {
    for (int idx = tid; idx < 2 * 64 * 32; idx += 512) {
      int n = idx >> 11, rq = idx & 2047, row = rq >> 5, g = rq & 31;
      int t = t0 + row;
      uint4 v = make_uint4(0, 0, 0, 0);
      if (t < T_DIM)
        v = *reinterpret_cast<const uint4*>(hbuf + ((size_t)(b * 4 + n0 + n) * T_DIM + t) * 256 + g * 8);
      *reinterpret_cast<uint4*>(&smem[(n * 64 + row) * EPAD + g * 8]) = v;
    }
  };

  f32x4 ymax[4][4];   // [pt][m] persists; static indexing only
  #pragma unroll
  for (int pt = 0; pt < 4; ++pt)
    #pragma unroll
    for (int m = 0; m < 4; ++m) ymax[pt][m] = (f32x4){0.f, 0.f, 0.f, 0.f};

  #pragma unroll 1
  for (int pair = 0; pair < 2; ++pair) {
    stage_pair(pair * 2);
    __syncthreads();
    #pragma unroll 1
    for (int n = 0; n < 2; ++n) {
      #pragma unroll
      for (int pt = 0; pt < 4; ++pt) {         // UNROLLED -> static ymax[pt]
        const int rowblk = w * 4 + pt;
        f32x4 acc[4];
        {
          float bv = b2[w * 64 + pt * 16 + lr];
          #pragma unroll
          for (int m = 0; m < 4; ++m) acc[m] = (f32x4){bv, bv, bv, bv};
        }
        #pragma unroll
        for (int kb = 0; kb < 8; ++kb) {
          bf16x8 bb = *reinterpret_cast<const bf16x8*>(W2f + ((size_t)(rowblk * 8 + kb) * 64 + lane) * 8);
          #pragma unroll
          for (int m = 0; m < 4; ++m) {
            bf16x8 a = *reinterpret_cast<const bf16x8*>(&smem[(n * 64 + m * 16 + lr) * EPAD + kb * 32 + lk]);
            acc[m] = __builtin_amdgcn_mfma_f32_16x16x32_bf16(a, bb, acc[m], 0, 0, 0);
          }
        }
        #pragma unroll
        for (int m = 0; m < 4; ++m)
          #pragma unroll
          for (int i = 0; i < 4; ++i) {
            float v = acc[m][i];
            v = v > 0.f ? v : 0.f;
            ymax[pt][m][i] = fmaxf(ymax[pt][m][i], v);
          }
      }
    }
    __syncthreads();   // all reads done before next stage / Y overwrite
  }

  // Y (bf16) into smem
  unsigned short* Y = smem;
  #pragma unroll
  for (int pt = 0; pt < 4; ++pt)
    #pragma unroll
    for (int m = 0; m < 4; ++m)
      #pragma unroll
      for (int i = 0; i < 4; ++i)
        Y[(m * 16 + rgrp + i) * YPAD + w * 64 + pt * 16 + lr] = f2b(ymax[pt][m][i]);
  __syncthreads();

  float dwv[9][8];
  #pragma unroll
  for (int o = 0; o < 9; ++o)
    #pragma unroll
    for (int j = 0; j < 8; ++j) dwv[o][j] = dwt[o * 512 + lane * 8 + j];

  #pragma unroll 1
  for (int r = 0; r < 8; ++r) {
    int row = w * 8 + r;
    int t = t0 + row;
    float yv[8];
    #pragma unroll
    for (int j = 0; j < 8; ++j) yv[j] = b2f(Y[row * YPAD + lane * 8 + j]);
    float zp[9];
    #pragma unroll
    for (int o = 0; o < 9; ++o) {
      float p = 0.f;
      #pragma unroll
      for (int j = 0; j < 8; ++j) p += yv[j] * dwv[o][j];
      zp[o] = p;
    }
    #pragma unroll
    for (int o = 0; o < 9; ++o) {
      #pragma unroll
      for (int sft = 32; sft > 0; sft >>= 1) zp[o] += __shfl_xor(zp[o], sft);
    }
    if (lane == 0 && t < T_DIM) {
      #pragma unroll
      for (int o = 0; o < 9; ++o) z[((size_t)b * T_DIM + t) * 9 + o] = zp[o] + dbv[o];
    }
  }
}

// ---------- launcher (r18 split path) ----------
extern "C" void kernel_launch(void* const* d_in, const int* in_sizes, int n_in,
                              void* d_out, int out_size, void* d_ws, size_t ws_size,
                              hipStream_t stream) {
  const float* x   = (const float*)d_in[0];
  const float* e0w = (const float*)d_in[1];
  const float* e0b = (const float*)d_in[2];
  const float* ew  = (const float*)d_in[3];
  const float* eb  = (const float*)d_in[4];
  const float* sw  = (const float*)d_in[5];
  const float* cl  = (const float*)d_in[6];
  const float* cr  = (const float*)d_in[7];
  const float* e2w = (const float*)d_in[8];
  const float* e2b = (const float*)d_in[9];
  const float* dw  = (const float*)d_in[10];
  const float* db  = (const float*)d_in[11];
  float* z = (float*)d_out;

  char* ws = (char*)d_ws;
  const size_t S_BYTES = (size_t)BN * T_DIM * 256 * 2;   // 131,072,000 bf16 plane
  unsigned short* hbuf = (unsigned short*)ws;                 // bf16 h
  unsigned short* sbuf = (unsigned short*)(ws + S_BYTES);     // bf16 s
  unsigned short* wbf  = (unsigned short*)(ws + 2 * S_BYTES);

  unsigned short* w1_0 = wbf;                  // frag-order [512][128]
  unsigned short* wexp = w1_0 + 512 * 128;     // frag-order [5][512][256]
  unsigned short* wshr = wexp + 5 * 512 * 256; // frag-order [6][256][512]
  unsigned short* w2   = wshr + 6 * 256 * 512; // frag-order [512][256]

  cvt_weights<<<800, 256, 0, stream>>>(e0w, ew, sw, e2w, wbf);

  dim3 gA(BN, 32);   // 64-row tiles over T=2000
  dim3 gB(BN, 10);   // 200-row strips

  layer_fused<128, true><<<gA, 512, 0, stream>>>(x, w1_0, e0b, wshr, sbuf);
  fsmn_kernel<false><<<gB, 256, 0, stream>>>(sbuf, cl, cr, hbuf);
  for (int i = 1; i < 6; ++i) {
    layer_fused<256, false><<<gA, 512, 0, stream>>>(
        hbuf, wexp + (size_t)(i - 1) * 512 * 256, eb + (i - 1) * 512,
        wshr + (size_t)i * 256 * 512, sbuf);
    fsmn_kernel<true><<<gB, 256, 0, stream>>>(sbuf, cl + i * 256 * 20, cr + i * 256, hbuf);
  }

  expand2_max_dec<<<dim3(32, 32), 512, 0, stream>>>(hbuf, w2, e2b, dw, db, z);
}

// Round 23
// 1637.096 us; speedup vs baseline: 1.2207x; 1.2207x over previous
//
#include <hip/hip_runtime.h>
#include <hip/hip_bf16.h>

// ---------- types ----------
typedef __bf16 bf16x8 __attribute__((ext_vector_type(8)));
typedef float  f32x4  __attribute__((ext_vector_type(4)));

__device__ __forceinline__ unsigned short f2b(float f) {
  __hip_bfloat16 h = __float2bfloat16(f);
  return __builtin_bit_cast(unsigned short, h);
}
__device__ __forceinline__ float b2f(unsigned short u) {
  unsigned int v = ((unsigned int)u) << 16;
  return __builtin_bit_cast(float, v);
}

constexpr int T_DIM = 2000;
constexpr int BN    = 128;   // B*N = 32*4

// ---------- weight conversion (frag-order for W1/Sw/W2) ----------
__device__ __forceinline__ void swz8(const float* __restrict__ src, int srcK,
                                     int rowblk, int kblk, int lane,
                                     unsigned short* dst8) {
  int row = rowblk * 16 + (lane & 15);
  int k0  = kblk * 32 + (lane >> 4) * 8;
  #pragma unroll
  for (int j = 0; j < 8; ++j) {
    int k = k0 + j;
    dst8[j] = (k < srcK) ? f2b(src[row * srcK + k]) : (unsigned short)0;
  }
}

__global__ __launch_bounds__(256)
void cvt_weights(const float* __restrict__ e0w, const float* __restrict__ ew,
                 const float* __restrict__ sw,  const float* __restrict__ e2w,
                 unsigned short* __restrict__ out) {
  const int G0 = 512 * 128 / 8;        // expand0 (K padded to 128)
  const int G1 = 5 * 512 * 256 / 8;    // expand_w
  const int G2 = 6 * 256 * 512 / 8;    // shrink_w
  const int G3 = 512 * 256 / 8;        // expand2_w
  int g = blockIdx.x * 256 + threadIdx.x;
  if (g >= G0 + G1 + G2 + G3) return;

  unsigned short tmp[8];
  if (g < G0) {
    int lane = g & 63, fid = g >> 6;       // KB=4
    int kblk = fid & 3, rowblk = fid >> 2;
    swz8(e0w, 120, rowblk, kblk, lane, tmp);
  } else if (g < G0 + G1) {
    int gg = g - G0;
    int mat = gg / 16384, r = gg % 16384;  // KB=8
    int lane = r & 63, fid = r >> 6;
    int kblk = fid & 7, rowblk = fid >> 3;
    swz8(ew + (size_t)mat * 512 * 256, 256, rowblk, kblk, lane, tmp);
  } else if (g < G0 + G1 + G2) {
    int gg = g - G0 - G1;
    int mat = gg / 16384, r = gg % 16384;  // KB=16
    int lane = r & 63, fid = r >> 6;
    int kblk = fid & 15, rowblk = fid >> 4;
    swz8(sw + (size_t)mat * 256 * 512, 512, rowblk, kblk, lane, tmp);
  } else {
    int gg = g - G0 - G1 - G2;             // W2 512x256, KB=8
    int lane = gg & 63, fid = gg >> 6;
    int kblk = fid & 7, rowblk = fid >> 3;
    swz8(e2w, 256, rowblk, kblk, lane, tmp);
  }
  #pragma unroll
  for (int j = 0; j < 8; ++j) out[(size_t)g * 8 + j] = tmp[j];
}

// ---------- fused expand(+relu) -> shrink, 64-row tile, 8 waves ----------
// Phase-1 MFMA operands SWAPPED (W1 as A-operand): packed ushort4 Elds write.
template<int KIN, bool L0>
__global__ __launch_bounds__(512, 4)
void layer_fused(const void* __restrict__ hin_v,          // L0: f32 x; else bf16 h
                 const unsigned short* __restrict__ W1,  // frag-order [512][KIN]
                 const float* __restrict__ b1,           // [512]
                 const unsigned short* __restrict__ Sw,  // frag-order [256][512]
                 unsigned short* __restrict__ sout)      // [BN,T,256] bf16
{
  constexpr int APAD = KIN + 8;
  constexpr int EPAD = 136;
  constexpr int KB1  = KIN / 32;       // 4 (L0) or 8
  constexpr int PB   = (KB1 < 4) ? KB1 : 4;   // prefetch batch size
  __shared__ unsigned short Alds[64 * APAD];
  __shared__ unsigned short Elds[64 * EPAD];

  const int bn  = blockIdx.x;
  const int t0  = blockIdx.y * 64;
  const int tid = threadIdx.x;

  if constexpr (L0) {
    const float* hin = (const float*)hin_v;
    constexpr int QUADS = KIN / 4;
    for (int idx = tid; idx < 64 * QUADS; idx += 512) {
      int row = idx / QUADS, q = idx % QUADS;
      int t = t0 + row;
      float4 v = make_float4(0.f, 0.f, 0.f, 0.f);
      if (t < T_DIM && q < 30) {
        const float* p = hin + ((size_t)((bn >> 2) * T_DIM + t) * 4 + (bn & 3)) * 120 + q * 4;
        v = *reinterpret_cast<const float4*>(p);
      }
      ushort4 u;
      u.x = f2b(v.x); u.y = f2b(v.y); u.z = f2b(v.z); u.w = f2b(v.w);
      *reinterpret_cast<ushort4*>(&Alds[row * APAD + q * 4]) = u;
    }
  } else {
    const unsigned short* hin = (const unsigned short*)hin_v;
    for (int idx = tid; idx < 64 * 32; idx += 512) {   // 32 x 8-ushort groups/row
      int row = idx >> 5, g = idx & 31;
      int t = t0 + row;
      uint4 v = make_uint4(0, 0, 0, 0);
      if (t < T_DIM)
        v = *reinterpret_cast<const uint4*>(hin + ((size_t)bn * T_DIM + t) * 256 + g * 8);
      *reinterpret_cast<uint4*>(&Alds[row * APAD + g * 8]) = v;
    }
  }

  const int w    = tid >> 6;          // wave 0..7
  const int lane = tid & 63;
  const int lr   = lane & 15;
  const int lk   = (lane >> 4) * 8;
  const int rgrp = (lane >> 4) * 4;

  auto ldW1 = [&](int c, int kb) {
    int rowblk = c * 8 + w;
    return *reinterpret_cast<const bf16x8*>(W1 + ((size_t)(rowblk * KB1 + kb) * 64 + lane) * 8);
  };

  bf16x8 w1p[PB];
  #pragma unroll
  for (int u = 0; u < PB; ++u) w1p[u] = ldW1(0, u);

  __syncthreads();

  f32x4 acc2[2][4];                   // [pt][m]
  #pragma unroll
  for (int pt = 0; pt < 2; ++pt)
    #pragma unroll
    for (int m = 0; m < 4; ++m) acc2[pt][m] = (f32x4){0.f, 0.f, 0.f, 0.f};

  #pragma unroll
  for (int c = 0; c < 4; ++c) {
    // ---- phase 1 (swapped): acc1[m][i] = E[t=m*16+lr][ecol=w*16+rgrp+i] ----
    f32x4 acc1[4];
    {
      float4 bv = *reinterpret_cast<const float4*>(&b1[c * 128 + w * 16 + rgrp]);
      #pragma unroll
      for (int m = 0; m < 4; ++m) acc1[m] = (f32x4){bv.x, bv.y, bv.z, bv.w};
    }
    #pragma unroll
    for (int u = 0; u < PB; ++u) {
      #pragma unroll
      for (int m = 0; m < 4; ++m) {
        bf16x8 a = *reinterpret_cast<const bf16x8*>(&Alds[(m * 16 + lr) * APAD + u * 32 + lk]);
        acc1[m] = __builtin_amdgcn_mfma_f32_16x16x32_bf16(w1p[u], a, acc1[m], 0, 0, 0);
      }
    }
    if constexpr (KB1 > PB) {
      bf16x8 bfr[KB1 - PB];
      #pragma unroll
      for (int u = 0; u < KB1 - PB; ++u) bfr[u] = ldW1(c, PB + u);
      #pragma unroll
      for (int u = 0; u < KB1 - PB; ++u) {
        #pragma unroll
        for (int m = 0; m < 4; ++m) {
          bf16x8 a = *reinterpret_cast<const bf16x8*>(&Alds[(m * 16 + lr) * APAD + (PB + u) * 32 + lk]);
          acc1[m] = __builtin_amdgcn_mfma_f32_16x16x32_bf16(bfr[u], a, acc1[m], 0, 0, 0);
        }
      }
    }
    // relu + packed ushort4 write: row = m*16+lr, cols = w*16+rgrp..+3
    #pragma unroll
    for (int m = 0; m < 4; ++m) {
      ushort4 u4;
      float v0 = acc1[m][0]; v0 = v0 > 0.f ? v0 : 0.f;
      float v1 = acc1[m][1]; v1 = v1 > 0.f ? v1 : 0.f;
      float v2 = acc1[m][2]; v2 = v2 > 0.f ? v2 : 0.f;
      float v3 = acc1[m][3]; v3 = v3 > 0.f ? v3 : 0.f;
      u4.x = f2b(v0); u4.y = f2b(v1); u4.z = f2b(v2); u4.w = f2b(v3);
      *reinterpret_cast<ushort4*>(&Elds[(m * 16 + lr) * EPAD + w * 16 + rgrp]) = u4;
    }
    // phase-2 B batch A (kb2 0..1), issued before the barrier
    bf16x8 b2a[4];
    #pragma unroll
    for (int u = 0; u < 4; ++u) {              // kb2 = u>>1, pt = u&1
      int rowblk = w * 2 + (u & 1);
      int kblk   = c * 4 + (u >> 1);
      b2a[u] = *reinterpret_cast<const bf16x8*>(Sw + ((size_t)(rowblk * 16 + kblk) * 64 + lane) * 8);
    }
    __syncthreads();
    // phase-2 B batch B (kb2 2..3) + next-c W1 prefetch under phase-2 MFMAs
    bf16x8 b2b[4];
    #pragma unroll
    for (int u = 0; u < 4; ++u) {
      int rowblk = w * 2 + (u & 1);
      int kblk   = c * 4 + 2 + (u >> 1);
      b2b[u] = *reinterpret_cast<const bf16x8*>(Sw + ((size_t)(rowblk * 16 + kblk) * 64 + lane) * 8);
    }
    if (c < 3) {
      #pragma unroll
      for (int u = 0; u < PB; ++u) w1p[u] = ldW1(c + 1, u);
    }
    // ---- phase 2: S cols [w*32,+32) += E_chunk * Sw^T ----
    #pragma unroll
    for (int kq = 0; kq < 2; ++kq) {
      bf16x8 a2[4];
      #pragma unroll
      for (int m = 0; m < 4; ++m)
        a2[m] = *reinterpret_cast<const bf16x8*>(&Elds[(m * 16 + lr) * EPAD + kq * 32 + lk]);
      #pragma unroll
      for (int pt = 0; pt < 2; ++pt)
        #pragma unroll
        for (int m = 0; m < 4; ++m)
          acc2[pt][m] = __builtin_amdgcn_mfma_f32_16x16x32_bf16(a2[m], b2a[kq * 2 + pt], acc2[pt][m], 0, 0, 0);
    }
    #pragma unroll
    for (int kq = 0; kq < 2; ++kq) {
      bf16x8 a2[4];
      #pragma unroll
      for (int m = 0; m < 4; ++m)
        a2[m] = *reinterpret_cast<const bf16x8*>(&Elds[(m * 16 + lr) * EPAD + (2 + kq) * 32 + lk]);
      #pragma unroll
      for (int pt = 0; pt < 2; ++pt)
        #pragma unroll
        for (int m = 0; m < 4; ++m)
          acc2[pt][m] = __builtin_amdgcn_mfma_f32_16x16x32_bf16(a2[m], b2b[kq * 2 + pt], acc2[pt][m], 0, 0, 0);
    }
    if (c < 3) __syncthreads();   // single Elds: drain reads before next write
  }

  // epilogue: col = w*32 + pt*16 + lr, t = t0 + m*16 + rgrp + i
  #pragma unroll
  for (int pt = 0; pt < 2; ++pt)
    #pragma unroll
    for (int m = 0; m < 4; ++m)
      #pragma unroll
      for (int i = 0; i < 4; ++i) {
        int t = t0 + m * 16 + rgrp + i;
        if (t < T_DIM)
          sout[((size_t)bn * T_DIM + t) * 256 + w * 32 + pt * 16 + lr] = f2b(acc2[pt][m][i]);
      }
}

// ---------- FSMN memory block + residual (h bf16), rolling reg window ------
template<bool RES, bool GUARD>
__device__ __forceinline__ void fsmn_body(const unsigned short* __restrict__ scol,
                                          unsigned short* __restrict__ hcol, int t0,
                                          const float* wlv, float wrv) {
  float sv[40];
  #pragma unroll
  for (int j = 0; j < 40; ++j) {
    int t = t0 + j - 19;
    sv[j] = (!GUARD || ((unsigned)t < (unsigned)T_DIM)) ? b2f(scol[(ptrdiff_t)t * 256]) : 0.f;
  }
  #pragma unroll 1
  for (int ch = 0; ch < 10; ++ch) {
    int tb = t0 + ch * 20;
    #pragma unroll
    for (int j = 0; j < 20; ++j) {
      float acc = sv[j + 19] + wrv * sv[j + 20];
      #pragma unroll
      for (int k = 0; k < 20; ++k) acc += wlv[k] * sv[j + k];
      size_t off = (size_t)(tb + j) * 256;
      float prev = RES ? b2f(hcol[off]) : 0.f;
      hcol[off] = f2b(prev + acc);
    }
    if (ch < 9) {
      #pragma unroll
      for (int j = 0; j < 20; ++j) sv[j] = sv[j + 20];
      #pragma unroll
      for (int j = 20; j < 40; ++j) {
        int t = tb + j + 1;
        sv[j] = (!GUARD || ((unsigned)t < (unsigned)T_DIM)) ? b2f(scol[(ptrdiff_t)t * 256]) : 0.f;
      }
    }
  }
}

template<bool RES>
__global__ __launch_bounds__(256)
void fsmn_kernel(const unsigned short* __restrict__ s,
                 const float* __restrict__ wl,
                 const float* __restrict__ wr,
                 unsigned short* __restrict__ hbuf)   // bf16 h
{
  const int bn = blockIdx.x;
  const int t0 = blockIdx.y * 200;
  const int p  = threadIdx.x;

  float wlv[20];
  #pragma unroll
  for (int k = 0; k < 20; ++k) wlv[k] = wl[p * 20 + k];
  const float wrv = wr[p];

  const unsigned short* scol = s + (size_t)bn * T_DIM * 256 + p;
  unsigned short* hcol = hbuf + (size_t)bn * T_DIM * 256 + p;

  bool safe = (t0 >= 19) && (t0 + 200 <= T_DIM - 1);
  if (safe) fsmn_body<RES, false>(scol, hcol, t0, wlv, wrv);
  else      fsmn_body<RES, true >(scol, hcol, t0, wlv, wrv);
}

// ---------- expand2 + relu + channel-max + decoder (fused; h bf16) ----------
// Uncapped VGPR; 135 KB LDS -> 1 blk/CU (min-wave hints only cause spill).
__global__ __launch_bounds__(512)
void expand2_max_dec(const unsigned short* __restrict__ hbuf,  // [BN,T,256] bf16
                     const unsigned short* __restrict__ W2f,   // frag-order [512][256]
                     const float* __restrict__ b2,             // [512]
                     const float* __restrict__ dwt,            // [9][512]
                     const float* __restrict__ dbv,            // [9]
                     float* __restrict__ z)                    // [32,T,9]
{
  constexpr int EPAD = 264;
  constexpr int YPAD = 520;
  __shared__ unsigned short smem[4 * 64 * EPAD];

  const int b   = blockIdx.x;
  const int t0  = blockIdx.y * 64;
  const int tid = threadIdx.x;

  for (int idx = tid; idx < 4 * 64 * 32; idx += 512) {   // 16B bf16 copies
    int n = idx >> 11, rq = idx & 2047, row = rq >> 5, g = rq & 31;
    int t = t0 + row;
    uint4 v = make_uint4(0, 0, 0, 0);
    if (t < T_DIM)
      v = *reinterpret_cast<const uint4*>(hbuf + ((size_t)(b * 4 + n) * T_DIM + t) * 256 + g * 8);
    *reinterpret_cast<uint4*>(&smem[(n * 64 + row) * EPAD + g * 8]) = v;
  }
  __syncthreads();

  const int w    = tid >> 6;
  const int lane = tid & 63;
  const int lr   = lane & 15;
  const int lk   = (lane >> 4) * 8;
  const int rgrp = (lane >> 4) * 4;

  f32x4 ymax[4][4];   // [pt][m] persists across n; static indexing only
  #pragma unroll
  for (int pt = 0; pt < 4; ++pt)
    #pragma unroll
    for (int m = 0; m < 4; ++m) ymax[pt][m] = (f32x4){0.f, 0.f, 0.f, 0.f};

  #pragma unroll 1
  for (int n = 0; n < 4; ++n) {
    #pragma unroll
    for (int pt = 0; pt < 4; ++pt) {           // UNROLLED -> static ymax[pt]
      const int rowblk = w * 4 + pt;
      f32x4 acc[4];
      {
        float bv = b2[w * 64 + pt * 16 + lr];
        #pragma unroll
        for (int m = 0; m < 4; ++m) acc[m] = (f32x4){bv, bv, bv, bv};
      }
      #pragma unroll
      for (int kb = 0; kb < 8; ++kb) {
        bf16x8 bb = *reinterpret_cast<const bf16x8*>(W2f + ((size_t)(rowblk * 8 + kb) * 64 + lane) * 8);
        #pragma unroll
        for (int m = 0; m < 4; ++m) {
          bf16x8 a = *reinterpret_cast<const bf16x8*>(&smem[(n * 64 + m * 16 + lr) * EPAD + kb * 32 + lk]);
          acc[m] = __builtin_amdgcn_mfma_f32_16x16x32_bf16(a, bb, acc[m], 0, 0, 0);
        }
      }
      #pragma unroll
      for (int m = 0; m < 4; ++m)
        #pragma unroll
        for (int i = 0; i < 4; ++i) {
          float v = acc[m][i];
          v = v > 0.f ? v : 0.f;
          ymax[pt][m][i] = fmaxf(ymax[pt][m][i], v);
        }
    }
  }
  __syncthreads();   // A-tiles dead; reuse smem for Y

  float* Y = reinterpret_cast<float*>(smem);
  #pragma unroll
  for (int pt = 0; pt < 4; ++pt)
    #pragma unroll
    for (int m = 0; m < 4; ++m)
      #pragma unroll
      for (int i = 0; i < 4; ++i)
        Y[(m * 16 + rgrp + i) * YPAD + w * 64 + pt * 16 + lr] = ymax[pt][m][i];
  __syncthreads();

  float dwv[9][8];
  #pragma unroll
  for (int o = 0; o < 9; ++o)
    #pragma unroll
    for (int j = 0; j < 8; ++j) dwv[o][j] = dwt[o * 512 + lane * 8 + j];

  #pragma unroll 1
  for (int r = 0; r < 8; ++r) {
    int row = w * 8 + r;
    int t = t0 + row;
    float yv[8];
    #pragma unroll
    for (int j = 0; j < 8; ++j) yv[j] = Y[row * YPAD + lane * 8 + j];
    float zp[9];
    #pragma unroll
    for (int o = 0; o < 9; ++o) {
      float p = 0.f;
      #pragma unroll
      for (int j = 0; j < 8; ++j) p += yv[j] * dwv[o][j];
      zp[o] = p;
    }
    #pragma unroll
    for (int o = 0; o < 9; ++o) {
      #pragma unroll
      for (int sft = 32; sft > 0; sft >>= 1) zp[o] += __shfl_xor(zp[o], sft);
    }
    if (lane == 0 && t < T_DIM) {
      #pragma unroll
      for (int o = 0; o < 9; ++o) z[((size_t)b * T_DIM + t) * 9 + o] = zp[o] + dbv[o];
    }
  }
}

// ---------- launcher ----------
extern "C" void kernel_launch(void* const* d_in, const int* in_sizes, int n_in,
                              void* d_out, int out_size, void* d_ws, size_t ws_size,
                              hipStream_t stream) {
  const float* x   = (const float*)d_in[0];
  const float* e0w = (const float*)d_in[1];
  const float* e0b = (const float*)d_in[2];
  const float* ew  = (const float*)d_in[3];
  const float* eb  = (const float*)d_in[4];
  const float* sw  = (const float*)d_in[5];
  const float* cl  = (const float*)d_in[6];
  const float* cr  = (const float*)d_in[7];
  const float* e2w = (const float*)d_in[8];
  const float* e2b = (const float*)d_in[9];
  const float* dw  = (const float*)d_in[10];
  const float* db  = (const float*)d_in[11];
  float* z = (float*)d_out;

  char* ws = (char*)d_ws;
  const size_t S_BYTES = (size_t)BN * T_DIM * 256 * 2;   // 131,072,000 bf16 plane
  unsigned short* hbuf = (unsigned short*)ws;                 // bf16 h
  unsigned short* sbuf = (unsigned short*)(ws + S_BYTES);     // bf16 s
  unsigned short* wbf  = (unsigned short*)(ws + 2 * S_BYTES);

  unsigned short* w1_0 = wbf;                  // frag-order [512][128]
  unsigned short* wexp = w1_0 + 512 * 128;     // frag-order [5][512][256]
  unsigned short* wshr = wexp + 5 * 512 * 256; // frag-order [6][256][512]
  unsigned short* w2   = wshr + 6 * 256 * 512; // frag-order [512][256]

  cvt_weights<<<800, 256, 0, stream>>>(e0w, ew, sw, e2w, wbf);

  dim3 gA(BN, 32);   // 64-row tiles over T=2000
  dim3 gB(BN, 10);   // 200-row strips

  layer_fused<128, true><<<gA, 512, 0, stream>>>(x, w1_0, e0b, wshr, sbuf);
  fsmn_kernel<false><<<gB, 256, 0, stream>>>(sbuf, cl, cr, hbuf);
  for (int i = 1; i < 6; ++i) {
    layer_fused<256, false><<<gA, 512, 0, stream>>>(
        hbuf, wexp + (size_t)(i - 1) * 512 * 256, eb + (i - 1) * 512,
        wshr + (size_t)i * 256 * 512, sbuf);
    fsmn_kernel<true><<<gB, 256, 0, stream>>>(sbuf, cl + i * 256 * 20, cr + i * 256, hbuf);
  }

  expand2_max_dec<<<dim3(32, 32), 512, 0, stream>>>(hbuf, w2, e2b, dw, db, z);
}